// Round 2
// baseline (133.673 us; speedup 1.0000x reference)
//
#include <hip/hip_runtime.h>
#include <math.h>

// Beamline: D(0.45) [Q_c D(0.9)]x19 Q_19 D(0.45). Output = hypot(std(x)-s, std(y)-s).
// Only final x,y matter -> final px,py, z-channel, n_slices all dead.
// Decomposition:
//   x_f = m11(pz)*x0 + m12(pz)*px0  (exact chromatic linear map, deg-7 poly in pz)
//       + cubic(x0,px0,y0,py0)      (first-order drift-nonlinearity kicks at pz=0)
// Prep kernel (f64) builds 32 Horner coeffs + 20 cubic coeffs into d_ws.

#define SIGMA_T 0.005
#define EPSQ 2.220446049250313e-16
#define PZ_A 6.5e-3
#define NNODE 8
#define MAXQ 64

struct M2 { double a11, a12, a21, a22; };

// quad 2x2 via signed-u series: u = A*L^2, C=sum u^k/(2k)!, S=sum u^k/(2k+1)!
// cos/cosh and sin/sinh unify; matches Bmad quad_mat2_calc to ~1e-17 for |u|<=0.05.
__device__ inline M2 quadmatS(double A, double rp, double L) {
    double u = A * L * L;
    double C = fma(u, fma(u, fma(u, fma(u, fma(u, fma(u, 1.0/479001600.0, 1.0/3628800.0),
                    1.0/40320.0), 1.0/720.0), 1.0/24.0), 0.5), 1.0);
    double S = fma(u, fma(u, fma(u, fma(u, fma(u, fma(u, 1.0/6227020800.0, 1.0/39916800.0),
                    1.0/362880.0), 1.0/5040.0), 1.0/120.0), 1.0/6.0), 1.0);
    M2 m;
    double LS = L * S;
    m.a11 = C;
    m.a12 = LS / rp;
    m.a21 = A * LS * rp;
    m.a22 = C;
    return m;
}
__device__ inline void lmul(M2& M, const M2& E) {  // M <- E*M
    double n11 = E.a11*M.a11 + E.a12*M.a21;
    double n12 = E.a11*M.a12 + E.a12*M.a22;
    double n21 = E.a21*M.a11 + E.a22*M.a21;
    double n22 = E.a21*M.a12 + E.a22*M.a22;
    M.a11=n11; M.a12=n12; M.a21=n21; M.a22=n22;
}
__device__ inline void ldrift(M2& M, double d) {   // M <- [[1,d],[0,1]]*M
    M.a11 += d * M.a21;
    M.a12 += d * M.a22;
}

// cf layout (floats at d_ws+64):
//  [0..31]  horner: f*8+k, f in {mx11,mx12,my11,my12}, k ascending power of t=pz/PZ_A
//  [32..41] Cx[10]: dx = x(C0 xx+C1 xp+C2 pp+C4 yy+C5 yq+C6 qq) + p(C3 pp+C7 yy+C8 yq+C9 qq)
//  [42..51] Cy[10]: symmetric
__global__ void prep_kernel(const float* __restrict__ k_set, int Q,
                            float* __restrict__ cf)
{
    __shared__ double Mn[NNODE][4];
    __shared__ double tn[NNODE];
    const int tid = threadIdx.x;
    if (Q > MAXQ) Q = MAXQ;

    if (tid < NNODE) {
        // Chebyshev node: exact chromatic linear lattice at pz = PZ_A*t
        double t = cos(M_PI * (2.0*tid + 1.0) / (2.0*NNODE));
        tn[tid] = t;
        double pz = PZ_A * t;
        double rp = 1.0 + pz;
        M2 X{1,0,0,1}, Y{1,0,0,1};
        ldrift(X, 0.45/rp); ldrift(Y, 0.45/rp);
        for (int c = 0; c < Q; ++c) {
            double k1n = (double)k_set[c] / rp;
            lmul(X, quadmatS(-k1n, rp, 0.1));
            lmul(Y, quadmatS( k1n, rp, 0.1));
            double d = ((c == Q-1) ? 0.45 : 0.9) / rp;
            ldrift(X, d); ldrift(Y, d);
        }
        Mn[tid][0]=X.a11; Mn[tid][1]=X.a12; Mn[tid][2]=Y.a11; Mn[tid][3]=Y.a12;
    } else if (tid == 64) {
        // pz=0 pass (separate wave, runs concurrently): cubic perturbation coeffs
        double ex[MAXQ+1], fxx[MAXQ+1], ey[MAXQ+1], fyy[MAXQ+1], Ld[MAXQ+1];
        double mx[MAXQ+1][4], my[MAXQ+1][4];
        M2 X{1,0,0,1}, Y{1,0,0,1};
        ex[0]=X.a21; fxx[0]=X.a22; ey[0]=Y.a21; fyy[0]=Y.a22; Ld[0]=0.45;
        ldrift(X, 0.45); ldrift(Y, 0.45);
        mx[0][0]=X.a11; mx[0][1]=X.a12; mx[0][2]=X.a21; mx[0][3]=X.a22;
        my[0][0]=Y.a11; my[0][1]=Y.a12; my[0][2]=Y.a21; my[0][3]=Y.a22;
        int nd = 1;
        for (int c = 0; c < Q; ++c) {
            double k1 = (double)k_set[c];
            lmul(X, quadmatS(-k1, 1.0, 0.1));
            lmul(Y, quadmatS( k1, 1.0, 0.1));
            double L = (c == Q-1) ? 0.45 : 0.9;
            ex[nd]=X.a21; fxx[nd]=X.a22; ey[nd]=Y.a21; fyy[nd]=Y.a22; Ld[nd]=L;
            ldrift(X, L); ldrift(Y, L);
            mx[nd][0]=X.a11; mx[nd][1]=X.a12; mx[nd][2]=X.a21; mx[nd][3]=X.a22;
            my[nd][0]=Y.a11; my[nd][1]=Y.a12; my[nd][2]=Y.a21; my[nd][3]=Y.a22;
            ++nd;
        }
        // X,Y = M_tot (pz=0). Kick at end of drift j: dx = L*pu*(pu^2+pv^2)/2,
        // propagated by R = [Mtot * inv(Mj)]_00 = t11*mj22 - t12*mj21 (det=1).
        double C[10], D[10];
        for (int i = 0; i < 10; ++i) { C[i]=0.0; D[i]=0.0; }
        for (int j = 0; j < nd; ++j) {
            double Rx = X.a11*mx[j][3] - X.a12*mx[j][2];
            double Ry = Y.a11*my[j][3] - Y.a12*my[j][2];
            double g = 0.5 * Ld[j] * Rx;
            double h = 0.5 * Ld[j] * Ry;
            double a = ex[j], b = fxx[j], c2 = ey[j], d2 = fyy[j];
            C[0]+=g*a*a*a;   C[1]+=3.0*g*a*a*b; C[2]+=3.0*g*a*b*b; C[3]+=g*b*b*b;
            C[4]+=g*a*c2*c2; C[5]+=2.0*g*a*c2*d2; C[6]+=g*a*d2*d2;
            C[7]+=g*b*c2*c2; C[8]+=2.0*g*b*c2*d2; C[9]+=g*b*d2*d2;
            D[0]+=h*c2*c2*c2; D[1]+=3.0*h*c2*c2*d2; D[2]+=3.0*h*c2*d2*d2; D[3]+=h*d2*d2*d2;
            D[4]+=h*c2*a*a;  D[5]+=2.0*h*c2*a*b; D[6]+=h*c2*b*b;
            D[7]+=h*d2*a*a;  D[8]+=2.0*h*d2*a*b; D[9]+=h*d2*b*b;
        }
        for (int i = 0; i < 10; ++i) { cf[32+i]=(float)C[i]; cf[42+i]=(float)D[i]; }
    }
    __syncthreads();
    if (tid < 4) {
        // solve V c = Mn[:,tid], V[i][k] = tn[i]^k  (8x8 f64 Gauss, partial pivot)
        double A[NNODE][NNODE+1];
        for (int i = 0; i < NNODE; ++i) {
            double p = 1.0;
            for (int k = 0; k < NNODE; ++k) { A[i][k] = p; p *= tn[i]; }
            A[i][NNODE] = Mn[i][tid];
        }
        for (int col = 0; col < NNODE; ++col) {
            int piv = col;
            for (int r = col+1; r < NNODE; ++r)
                if (fabs(A[r][col]) > fabs(A[piv][col])) piv = r;
            if (piv != col)
                for (int k = col; k <= NNODE; ++k) { double tt=A[col][k]; A[col][k]=A[piv][k]; A[piv][k]=tt; }
            double inv = 1.0 / A[col][col];
            for (int r = col+1; r < NNODE; ++r) {
                double f = A[r][col] * inv;
                for (int k = col; k <= NNODE; ++k) A[r][k] -= f * A[col][k];
            }
        }
        double sol[NNODE];
        for (int i = NNODE-1; i >= 0; --i) {
            double s = A[i][NNODE];
            for (int k = i+1; k < NNODE; ++k) s -= A[i][k] * sol[k];
            sol[i] = s / A[i][i];
        }
        for (int k = 0; k < NNODE; ++k) cf[tid*8 + k] = (float)sol[k];
    }
}

__device__ inline float uniformf(const float* p) {
    return __int_as_float(__builtin_amdgcn_readfirstlane(__float_as_int(*p)));
}

__global__ __launch_bounds__(256) void beam_kernel(
    const float* __restrict__ xs, const float* __restrict__ pxs,
    const float* __restrict__ ys, const float* __restrict__ pys,
    const float* __restrict__ pzs, const float* __restrict__ cf,
    int n4, int ntail, double* __restrict__ acc)
{
    float h[32], Cx[10], Cy[10];
    #pragma unroll
    for (int k = 0; k < 32; ++k) h[k] = uniformf(cf + k);
    #pragma unroll
    for (int k = 0; k < 10; ++k) { Cx[k] = uniformf(cf + 32 + k); Cy[k] = uniformf(cf + 42 + k); }

    const float inva = (float)(1.0 / PZ_A);
    float s1x = 0.f, s2x = 0.f, s1y = 0.f, s2y = 0.f;

    auto track = [&](float x, float p, float y, float q, float pz) {
        float t = pz * inva;
        float m11 = h[7], m12 = h[15], n11 = h[23], n12 = h[31];
        #pragma unroll
        for (int k = 6; k >= 0; --k) {
            m11 = fmaf(m11, t, h[k]);
            m12 = fmaf(m12, t, h[8+k]);
            n11 = fmaf(n11, t, h[16+k]);
            n12 = fmaf(n12, t, h[24+k]);
        }
        float xx = x*x, xp = x*p, pp = p*p;
        float yy = y*y, yq = y*q, qq = q*q;
        float A1 = Cx[0]*xx; A1=fmaf(Cx[1],xp,A1); A1=fmaf(Cx[2],pp,A1);
        A1=fmaf(Cx[4],yy,A1); A1=fmaf(Cx[5],yq,A1); A1=fmaf(Cx[6],qq,A1);
        float A2 = Cx[3]*pp; A2=fmaf(Cx[7],yy,A2); A2=fmaf(Cx[8],yq,A2); A2=fmaf(Cx[9],qq,A2);
        float B1 = Cy[0]*yy; B1=fmaf(Cy[1],yq,B1); B1=fmaf(Cy[2],qq,B1);
        B1=fmaf(Cy[4],xx,B1); B1=fmaf(Cy[5],xp,B1); B1=fmaf(Cy[6],pp,B1);
        float B2 = Cy[3]*qq; B2=fmaf(Cy[7],xx,B2); B2=fmaf(Cy[8],xp,B2); B2=fmaf(Cy[9],pp,B2);
        float xf = fmaf(m11, x, m12*p); xf = fmaf(x, A1, xf); xf = fmaf(p, A2, xf);
        float yf = fmaf(n11, y, n12*q); yf = fmaf(y, B1, yf); yf = fmaf(q, B2, yf);
        s1x += xf; s2x = fmaf(xf, xf, s2x);
        s1y += yf; s2y = fmaf(yf, yf, s2y);
    };

    const int i = blockIdx.x * blockDim.x + threadIdx.x;
    if (i < n4) {
        float4 xv  = ((const float4*)xs)[i];
        float4 pxv = ((const float4*)pxs)[i];
        float4 yv  = ((const float4*)ys)[i];
        float4 pyv = ((const float4*)pys)[i];
        float4 pzv = ((const float4*)pzs)[i];
        track(xv.x, pxv.x, yv.x, pyv.x, pzv.x);
        track(xv.y, pxv.y, yv.y, pyv.y, pzv.y);
        track(xv.z, pxv.z, yv.z, pyv.z, pzv.z);
        track(xv.w, pxv.w, yv.w, pyv.w, pzv.w);
    }
    if (blockIdx.x == 0 && threadIdx.x == 0) {
        for (int r = 0; r < ntail; ++r) {
            int idx = 4*n4 + r;
            track(xs[idx], pxs[idx], ys[idx], pys[idx], pzs[idx]);
        }
    }

    for (int off = 32; off > 0; off >>= 1) {
        s1x += __shfl_down(s1x, off, 64);
        s2x += __shfl_down(s2x, off, 64);
        s1y += __shfl_down(s1y, off, 64);
        s2y += __shfl_down(s2y, off, 64);
    }
    __shared__ float red[4][4];
    const int lane = threadIdx.x & 63;
    const int wid  = threadIdx.x >> 6;
    if (lane == 0) {
        red[wid][0] = s1x; red[wid][1] = s2x;
        red[wid][2] = s1y; red[wid][3] = s2y;
    }
    __syncthreads();
    if (threadIdx.x == 0) {
        float a = 0.f, b = 0.f, c = 0.f, d = 0.f;
        const int nw = (blockDim.x + 63) >> 6;
        for (int w = 0; w < nw; ++w) {
            a += red[w][0]; b += red[w][1];
            c += red[w][2]; d += red[w][3];
        }
        atomicAdd(&acc[0], (double)a);
        atomicAdd(&acc[1], (double)b);
        atomicAdd(&acc[2], (double)c);
        atomicAdd(&acc[3], (double)d);
    }
}

__global__ void finalize_kernel(const double* __restrict__ acc,
                                float* __restrict__ out, int N)
{
    const double n  = (double)N;
    const double vx = (acc[1] - acc[0]*acc[0]/n) / (n - 1.0);
    const double vy = (acc[3] - acc[2]*acc[2]/n) / (n - 1.0);
    const double dx = sqrt(vx) - SIGMA_T;
    const double dy = sqrt(vy) - SIGMA_T;
    out[0] = (float)sqrt(dx*dx + dy*dy);
}

extern "C" void kernel_launch(void* const* d_in, const int* in_sizes, int n_in,
                              void* d_out, int out_size, void* d_ws, size_t ws_size,
                              hipStream_t stream) {
    const float* xs  = (const float*)d_in[0];
    const float* pxs = (const float*)d_in[1];
    const float* ys  = (const float*)d_in[2];
    const float* pys = (const float*)d_in[3];
    // d_in[4] = z : dead
    const float* pzs = (const float*)d_in[5];
    const float* ks  = (const float*)d_in[6];
    // d_in[7] = n_slices : dead (exact slice composition)

    const int N = in_sizes[0];
    const int Q = in_sizes[6];

    double* acc = (double*)d_ws;
    float*  cf  = (float*)((char*)d_ws + 64);
    hipMemsetAsync(d_ws, 0, 4 * sizeof(double), stream);

    prep_kernel<<<1, 128, 0, stream>>>(ks, Q, cf);

    const int n4 = N >> 2;
    const int ntail = N & 3;
    int blocks = (n4 + 255) / 256;
    if (blocks < 1) blocks = 1;
    beam_kernel<<<blocks, 256, 0, stream>>>(xs, pxs, ys, pys, pzs, cf, n4, ntail, acc);
    finalize_kernel<<<1, 1, 0, stream>>>(acc, (float*)d_out, N);
}

// Round 3
// 37.049 us; speedup vs baseline: 3.6080x; 3.6080x over previous
//
#include <hip/hip_runtime.h>
#include <math.h>

// Beamline: D(0.45) [Q_c D(0.9)]x19 Q_19 D(0.45). Output = hypot(std(x)-s, std(y)-s).
// Only final x,y matter -> final px,py, z-channel, n_slices all dead.
// Decomposition:
//   x_f = m11(pz)*x0 + m12(pz)*px0  (exact chromatic linear map, deg-7 poly in pz)
//       + cubic(x0,px0,y0,py0)      (first-order drift-nonlinearity kicks at pz=0)
// Prep kernel (f64) builds 32 Horner coeffs + 20 cubic coeffs into d_ws.
// Reduction: per-block float4 partials (NO atomics - round-2 showed 7.8k
// same-line f64 atomics serialize at ~13ns each = 100us floor), f64 finalize.

#define SIGMA_T 0.005
#define PZ_A 6.5e-3
#define NNODE 8
#define MAXQ 64
#define MAXBLK 2048

struct M2 { double a11, a12, a21, a22; };

// quad 2x2 via signed-u series: u = A*L^2, C=sum u^k/(2k)!, S=sum u^k/(2k+1)!
// cos/cosh and sin/sinh unify; matches Bmad quad_mat2_calc to ~1e-17 for |u|<=0.05.
__device__ inline M2 quadmatS(double A, double rp, double L) {
    double u = A * L * L;
    double C = fma(u, fma(u, fma(u, fma(u, fma(u, fma(u, 1.0/479001600.0, 1.0/3628800.0),
                    1.0/40320.0), 1.0/720.0), 1.0/24.0), 0.5), 1.0);
    double S = fma(u, fma(u, fma(u, fma(u, fma(u, fma(u, 1.0/6227020800.0, 1.0/39916800.0),
                    1.0/362880.0), 1.0/5040.0), 1.0/120.0), 1.0/6.0), 1.0);
    M2 m;
    double LS = L * S;
    m.a11 = C;
    m.a12 = LS / rp;
    m.a21 = A * LS * rp;
    m.a22 = C;
    return m;
}
__device__ inline void lmul(M2& M, const M2& E) {  // M <- E*M
    double n11 = E.a11*M.a11 + E.a12*M.a21;
    double n12 = E.a11*M.a12 + E.a12*M.a22;
    double n21 = E.a21*M.a11 + E.a22*M.a21;
    double n22 = E.a21*M.a12 + E.a22*M.a22;
    M.a11=n11; M.a12=n12; M.a21=n21; M.a22=n22;
}
__device__ inline void ldrift(M2& M, double d) {   // M <- [[1,d],[0,1]]*M
    M.a11 += d * M.a21;
    M.a12 += d * M.a22;
}

// cf layout (floats at d_ws+64):
//  [0..31]  horner: f*8+k, f in {mx11,mx12,my11,my12}, k ascending power of t=pz/PZ_A
//  [32..41] Cx[10]: dx = x(C0 xx+C1 xp+C2 pp+C4 yy+C5 yq+C6 qq) + p(C3 pp+C7 yy+C8 yq+C9 qq)
//  [42..51] Cy[10]: symmetric
__global__ void prep_kernel(const float* __restrict__ k_set, int Q,
                            float* __restrict__ cf)
{
    __shared__ double Mn[NNODE][4];
    __shared__ double tn[NNODE];
    const int tid = threadIdx.x;
    if (Q > MAXQ) Q = MAXQ;

    if (tid < NNODE) {
        // Chebyshev node: exact chromatic linear lattice at pz = PZ_A*t
        double t = cos(M_PI * (2.0*tid + 1.0) / (2.0*NNODE));
        tn[tid] = t;
        double pz = PZ_A * t;
        double rp = 1.0 + pz;
        M2 X{1,0,0,1}, Y{1,0,0,1};
        ldrift(X, 0.45/rp); ldrift(Y, 0.45/rp);
        for (int c = 0; c < Q; ++c) {
            double k1n = (double)k_set[c] / rp;
            lmul(X, quadmatS(-k1n, rp, 0.1));
            lmul(Y, quadmatS( k1n, rp, 0.1));
            double d = ((c == Q-1) ? 0.45 : 0.9) / rp;
            ldrift(X, d); ldrift(Y, d);
        }
        Mn[tid][0]=X.a11; Mn[tid][1]=X.a12; Mn[tid][2]=Y.a11; Mn[tid][3]=Y.a12;
    } else if (tid == 64) {
        // pz=0 pass (separate wave): cubic perturbation coeffs.
        // Two sweeps, no arrays (arrays -> scratch -> slow, rule #20).
        // Sweep 1: total matrices at pz=0.
        M2 X{1,0,0,1}, Y{1,0,0,1};
        ldrift(X, 0.45); ldrift(Y, 0.45);
        for (int c = 0; c < Q; ++c) {
            double k1 = (double)k_set[c];
            lmul(X, quadmatS(-k1, 1.0, 0.1));
            lmul(Y, quadmatS( k1, 1.0, 0.1));
            double L = (c == Q-1) ? 0.45 : 0.9;
            ldrift(X, L); ldrift(Y, L);
        }
        // Sweep 2: prefix matrices on the fly; kick at end of drift j:
        // dx = L*pu*(pu^2+pv^2)/2, pu = e*x0 + f*px0 (prefix a21,a22 at drift
        // start), propagated by R = [Mtot*inv(Mj_end)]_00 = t11*mj22 - t12*mj21.
        double C[10], D[10];
        #pragma unroll
        for (int i = 0; i < 10; ++i) { C[i]=0.0; D[i]=0.0; }
        M2 Xp{1,0,0,1}, Yp{1,0,0,1};
        for (int j = 0; j <= Q; ++j) {
            double L = (j == 0 || j == Q) ? 0.45 : 0.9;
            double a = Xp.a21, b = Xp.a22, c2 = Yp.a21, d2 = Yp.a22;
            ldrift(Xp, L); ldrift(Yp, L);
            double Rx = X.a11*Xp.a22 - X.a12*Xp.a21;
            double Ry = Y.a11*Yp.a22 - Y.a12*Yp.a21;
            double g = 0.5 * L * Rx;
            double h = 0.5 * L * Ry;
            C[0]+=g*a*a*a;   C[1]+=3.0*g*a*a*b; C[2]+=3.0*g*a*b*b; C[3]+=g*b*b*b;
            C[4]+=g*a*c2*c2; C[5]+=2.0*g*a*c2*d2; C[6]+=g*a*d2*d2;
            C[7]+=g*b*c2*c2; C[8]+=2.0*g*b*c2*d2; C[9]+=g*b*d2*d2;
            D[0]+=h*c2*c2*c2; D[1]+=3.0*h*c2*c2*d2; D[2]+=3.0*h*c2*d2*d2; D[3]+=h*d2*d2*d2;
            D[4]+=h*c2*a*a;  D[5]+=2.0*h*c2*a*b; D[6]+=h*c2*b*b;
            D[7]+=h*d2*a*a;  D[8]+=2.0*h*d2*a*b; D[9]+=h*d2*b*b;
            if (j < Q) {
                double k1 = (double)k_set[j];
                lmul(Xp, quadmatS(-k1, 1.0, 0.1));
                lmul(Yp, quadmatS( k1, 1.0, 0.1));
            }
        }
        #pragma unroll
        for (int i = 0; i < 10; ++i) { cf[32+i]=(float)C[i]; cf[42+i]=(float)D[i]; }
    }
    __syncthreads();
    if (tid < 4) {
        // solve V c = Mn[:,tid], V[i][k] = tn[i]^k  (8x8 f64 Gauss, partial pivot)
        double A[NNODE][NNODE+1];
        for (int i = 0; i < NNODE; ++i) {
            double p = 1.0;
            for (int k = 0; k < NNODE; ++k) { A[i][k] = p; p *= tn[i]; }
            A[i][NNODE] = Mn[i][tid];
        }
        for (int col = 0; col < NNODE; ++col) {
            int piv = col;
            for (int r = col+1; r < NNODE; ++r)
                if (fabs(A[r][col]) > fabs(A[piv][col])) piv = r;
            if (piv != col)
                for (int k = col; k <= NNODE; ++k) { double tt=A[col][k]; A[col][k]=A[piv][k]; A[piv][k]=tt; }
            double inv = 1.0 / A[col][col];
            for (int r = col+1; r < NNODE; ++r) {
                double f = A[r][col] * inv;
                for (int k = col; k <= NNODE; ++k) A[r][k] -= f * A[col][k];
            }
        }
        double sol[NNODE];
        for (int i = NNODE-1; i >= 0; --i) {
            double s = A[i][NNODE];
            for (int k = i+1; k < NNODE; ++k) s -= A[i][k] * sol[k];
            sol[i] = s / A[i][i];
        }
        for (int k = 0; k < NNODE; ++k) cf[tid*8 + k] = (float)sol[k];
    }
}

__device__ inline float uniformf(const float* p) {
    return __int_as_float(__builtin_amdgcn_readfirstlane(__float_as_int(*p)));
}

__global__ __launch_bounds__(256) void beam_kernel(
    const float* __restrict__ xs, const float* __restrict__ pxs,
    const float* __restrict__ ys, const float* __restrict__ pys,
    const float* __restrict__ pzs, const float* __restrict__ cf,
    int n4, int ntail, float4* __restrict__ partials)
{
    float h[32], Cx[10], Cy[10];
    #pragma unroll
    for (int k = 0; k < 32; ++k) h[k] = uniformf(cf + k);
    #pragma unroll
    for (int k = 0; k < 10; ++k) { Cx[k] = uniformf(cf + 32 + k); Cy[k] = uniformf(cf + 42 + k); }

    const float inva = (float)(1.0 / PZ_A);
    float s1x = 0.f, s2x = 0.f, s1y = 0.f, s2y = 0.f;

    auto track = [&](float x, float p, float y, float q, float pz) {
        float t = pz * inva;
        float m11 = h[7], m12 = h[15], n11 = h[23], n12 = h[31];
        #pragma unroll
        for (int k = 6; k >= 0; --k) {
            m11 = fmaf(m11, t, h[k]);
            m12 = fmaf(m12, t, h[8+k]);
            n11 = fmaf(n11, t, h[16+k]);
            n12 = fmaf(n12, t, h[24+k]);
        }
        float xx = x*x, xp = x*p, pp = p*p;
        float yy = y*y, yq = y*q, qq = q*q;
        float A1 = Cx[0]*xx; A1=fmaf(Cx[1],xp,A1); A1=fmaf(Cx[2],pp,A1);
        A1=fmaf(Cx[4],yy,A1); A1=fmaf(Cx[5],yq,A1); A1=fmaf(Cx[6],qq,A1);
        float A2 = Cx[3]*pp; A2=fmaf(Cx[7],yy,A2); A2=fmaf(Cx[8],yq,A2); A2=fmaf(Cx[9],qq,A2);
        float B1 = Cy[0]*yy; B1=fmaf(Cy[1],yq,B1); B1=fmaf(Cy[2],qq,B1);
        B1=fmaf(Cy[4],xx,B1); B1=fmaf(Cy[5],xp,B1); B1=fmaf(Cy[6],pp,B1);
        float B2 = Cy[3]*qq; B2=fmaf(Cy[7],xx,B2); B2=fmaf(Cy[8],xp,B2); B2=fmaf(Cy[9],pp,B2);
        float xf = fmaf(m11, x, m12*p); xf = fmaf(x, A1, xf); xf = fmaf(p, A2, xf);
        float yf = fmaf(n11, y, n12*q); yf = fmaf(y, B1, yf); yf = fmaf(q, B2, yf);
        s1x += xf; s2x = fmaf(xf, xf, s2x);
        s1y += yf; s2y = fmaf(yf, yf, s2y);
    };

    const int gstride = gridDim.x * blockDim.x;
    for (int i = blockIdx.x * blockDim.x + threadIdx.x; i < n4; i += gstride) {
        float4 xv  = ((const float4*)xs)[i];
        float4 pxv = ((const float4*)pxs)[i];
        float4 yv  = ((const float4*)ys)[i];
        float4 pyv = ((const float4*)pys)[i];
        float4 pzv = ((const float4*)pzs)[i];
        track(xv.x, pxv.x, yv.x, pyv.x, pzv.x);
        track(xv.y, pxv.y, yv.y, pyv.y, pzv.y);
        track(xv.z, pxv.z, yv.z, pyv.z, pzv.z);
        track(xv.w, pxv.w, yv.w, pyv.w, pzv.w);
    }
    if (blockIdx.x == 0 && threadIdx.x == 0) {
        for (int r = 0; r < ntail; ++r) {
            int idx = 4*n4 + r;
            track(xs[idx], pxs[idx], ys[idx], pys[idx], pzs[idx]);
        }
    }

    // wave (64-lane) shuffle reduce, then LDS across 4 waves
    for (int off = 32; off > 0; off >>= 1) {
        s1x += __shfl_down(s1x, off, 64);
        s2x += __shfl_down(s2x, off, 64);
        s1y += __shfl_down(s1y, off, 64);
        s2y += __shfl_down(s2y, off, 64);
    }
    __shared__ float red[4][4];
    const int lane = threadIdx.x & 63;
    const int wid  = threadIdx.x >> 6;
    if (lane == 0) {
        red[wid][0] = s1x; red[wid][1] = s2x;
        red[wid][2] = s1y; red[wid][3] = s2y;
    }
    __syncthreads();
    if (threadIdx.x == 0) {
        float a = 0.f, b = 0.f, c = 0.f, d = 0.f;
        const int nw = (blockDim.x + 63) >> 6;
        for (int w = 0; w < nw; ++w) {
            a += red[w][0]; b += red[w][1];
            c += red[w][2]; d += red[w][3];
        }
        partials[blockIdx.x] = make_float4(a, b, c, d);  // no atomics
    }
}

__global__ __launch_bounds__(256) void finalize_kernel(
    const float4* __restrict__ partials, int nparts,
    float* __restrict__ out, int N)
{
    double a = 0.0, b = 0.0, c = 0.0, d = 0.0;
    for (int i = threadIdx.x; i < nparts; i += 256) {
        float4 p = partials[i];
        a += (double)p.x; b += (double)p.y;
        c += (double)p.z; d += (double)p.w;
    }
    for (int off = 32; off > 0; off >>= 1) {
        a += __shfl_down(a, off, 64);
        b += __shfl_down(b, off, 64);
        c += __shfl_down(c, off, 64);
        d += __shfl_down(d, off, 64);
    }
    __shared__ double red[4][4];
    const int lane = threadIdx.x & 63;
    const int wid  = threadIdx.x >> 6;
    if (lane == 0) {
        red[wid][0] = a; red[wid][1] = b; red[wid][2] = c; red[wid][3] = d;
    }
    __syncthreads();
    if (threadIdx.x == 0) {
        double sa = 0, sb = 0, sc = 0, sd = 0;
        for (int w = 0; w < 4; ++w) {
            sa += red[w][0]; sb += red[w][1];
            sc += red[w][2]; sd += red[w][3];
        }
        const double n  = (double)N;
        const double vx = (sb - sa*sa/n) / (n - 1.0);
        const double vy = (sd - sc*sc/n) / (n - 1.0);
        const double dx = sqrt(vx) - SIGMA_T;
        const double dy = sqrt(vy) - SIGMA_T;
        out[0] = (float)sqrt(dx*dx + dy*dy);
    }
}

extern "C" void kernel_launch(void* const* d_in, const int* in_sizes, int n_in,
                              void* d_out, int out_size, void* d_ws, size_t ws_size,
                              hipStream_t stream) {
    const float* xs  = (const float*)d_in[0];
    const float* pxs = (const float*)d_in[1];
    const float* ys  = (const float*)d_in[2];
    const float* pys = (const float*)d_in[3];
    // d_in[4] = z : dead
    const float* pzs = (const float*)d_in[5];
    const float* ks  = (const float*)d_in[6];
    // d_in[7] = n_slices : dead (exact slice composition)

    const int N = in_sizes[0];
    const int Q = in_sizes[6];

    float*  cf       = (float*)((char*)d_ws + 64);
    float4* partials = (float4*)((char*)d_ws + 4096);

    prep_kernel<<<1, 128, 0, stream>>>(ks, Q, cf);

    const int n4 = N >> 2;
    const int ntail = N & 3;
    int blocks = (n4 + 255) / 256;
    if (blocks < 1) blocks = 1;
    if (blocks > MAXBLK) blocks = MAXBLK;
    beam_kernel<<<blocks, 256, 0, stream>>>(xs, pxs, ys, pys, pzs, cf, n4, ntail, partials);
    finalize_kernel<<<1, 256, 0, stream>>>(partials, blocks, (float*)d_out, N);
}

// Round 4
// 31.341 us; speedup vs baseline: 4.2651x; 1.1821x over previous
//
#include <hip/hip_runtime.h>
#include <math.h>

// Beamline: D(0.45) [Q_c D(0.9)]x19 Q_19 D(0.45). Output = hypot(std(x)-s, std(y)-s).
// Only final x,y matter -> final px,py, z-channel, n_slices all dead.
// Decomposition:
//   x_f = m11(pz)*x0 + m12(pz)*px0  (exact chromatic linear map, deg-7 poly in pz)
//       + cubic(x0,px0,y0,py0)      (first-order drift-nonlinearity kicks at pz=0)
// Prep (f64): Chebyshev-node lattices + Newton divided-difference fit (register-
// resident, fully static indexing — round-3's Gauss pivot solve went to scratch
// and cost ~60us for one wave). Reduction: per-block float4 partials, no atomics
// (round-2: 7.8k same-line f64 atomics serialized = 100us floor).

#define SIGMA_T 0.005
#define PZ_A 6.5e-3
#define NNODE 8
#define MAXQ 64
#define MAXBLK 2048

// cos(pi*(2i+1)/16), i = 0..7
#define T0  0.9807852804032304
#define T1  0.8314696123025452
#define T2  0.5555702330196022
#define T3  0.1950903220161283
#define T4 (-0.1950903220161283)
#define T5 (-0.5555702330196022)
#define T6 (-0.8314696123025452)
#define T7 (-0.9807852804032304)

struct M2 { double a11, a12, a21, a22; };

// quad 2x2 via signed-u series: u = A*L^2, C=sum u^k/(2k)!, S=sum u^k/(2k+1)!
// cos/cosh and sin/sinh unify; matches Bmad quad_mat2_calc to ~1e-17 for |u|<=0.05.
__device__ inline M2 quadmatS(double A, double rp, double L) {
    double u = A * L * L;
    double C = fma(u, fma(u, fma(u, fma(u, fma(u, fma(u, 1.0/479001600.0, 1.0/3628800.0),
                    1.0/40320.0), 1.0/720.0), 1.0/24.0), 0.5), 1.0);
    double S = fma(u, fma(u, fma(u, fma(u, fma(u, fma(u, 1.0/6227020800.0, 1.0/39916800.0),
                    1.0/362880.0), 1.0/5040.0), 1.0/120.0), 1.0/6.0), 1.0);
    M2 m;
    double LS = L * S;
    m.a11 = C;
    m.a12 = LS / rp;
    m.a21 = A * LS * rp;
    m.a22 = C;
    return m;
}
__device__ inline void lmul(M2& M, const M2& E) {  // M <- E*M
    double n11 = E.a11*M.a11 + E.a12*M.a21;
    double n12 = E.a11*M.a12 + E.a12*M.a22;
    double n21 = E.a21*M.a11 + E.a22*M.a21;
    double n22 = E.a21*M.a12 + E.a22*M.a22;
    M.a11=n11; M.a12=n12; M.a21=n21; M.a22=n22;
}
__device__ inline void ldrift(M2& M, double d) {   // M <- [[1,d],[0,1]]*M
    M.a11 += d * M.a21;
    M.a12 += d * M.a22;
}

// cf layout (floats at d_ws+64):
//  [0..31]  horner: f*8+k, f in {mx11,mx12,my11,my12}, k ascending power of t=pz/PZ_A
//  [32..41] Cx[10]: dx = x(C0 xx+C1 xp+C2 pp+C4 yy+C5 yq+C6 qq) + p(C3 pp+C7 yy+C8 yq+C9 qq)
//  [42..51] Cy[10]: symmetric
__global__ void prep_kernel(const float* __restrict__ k_set, int Q,
                            float* __restrict__ cf)
{
    const double TN[NNODE] = {T0, T1, T2, T3, T4, T5, T6, T7};
    __shared__ double Mn[NNODE][4];
    const int tid = threadIdx.x;
    if (Q > MAXQ) Q = MAXQ;

    if (tid < NNODE) {
        // Chebyshev node: exact chromatic linear lattice at pz = PZ_A*t
        double pz = PZ_A * TN[tid];
        double rp = 1.0 + pz;
        M2 X{1,0,0,1}, Y{1,0,0,1};
        ldrift(X, 0.45/rp); ldrift(Y, 0.45/rp);
        for (int c = 0; c < Q; ++c) {
            double k1n = (double)k_set[c] / rp;
            lmul(X, quadmatS(-k1n, rp, 0.1));
            lmul(Y, quadmatS( k1n, rp, 0.1));
            double d = ((c == Q-1) ? 0.45 : 0.9) / rp;
            ldrift(X, d); ldrift(Y, d);
        }
        Mn[tid][0]=X.a11; Mn[tid][1]=X.a12; Mn[tid][2]=Y.a11; Mn[tid][3]=Y.a12;
    } else if (tid == 64) {
        // pz=0 pass (separate wave): cubic perturbation coeffs, register-resident.
        // Sweep 1: total matrices at pz=0.
        M2 X{1,0,0,1}, Y{1,0,0,1};
        ldrift(X, 0.45); ldrift(Y, 0.45);
        for (int c = 0; c < Q; ++c) {
            double k1 = (double)k_set[c];
            lmul(X, quadmatS(-k1, 1.0, 0.1));
            lmul(Y, quadmatS( k1, 1.0, 0.1));
            double L = (c == Q-1) ? 0.45 : 0.9;
            ldrift(X, L); ldrift(Y, L);
        }
        // Sweep 2: prefix matrices on the fly; kick at end of drift j:
        // dx = L*pu*(pu^2+pv^2)/2, pu = e*x0 + f*px0 (prefix a21,a22 at drift
        // start), propagated by R = [Mtot*inv(Mj_end)]_00 = t11*mj22 - t12*mj21.
        double C[10], D[10];
        #pragma unroll
        for (int i = 0; i < 10; ++i) { C[i]=0.0; D[i]=0.0; }
        M2 Xp{1,0,0,1}, Yp{1,0,0,1};
        for (int j = 0; j <= Q; ++j) {
            double L = (j == 0 || j == Q) ? 0.45 : 0.9;
            double a = Xp.a21, b = Xp.a22, c2 = Yp.a21, d2 = Yp.a22;
            ldrift(Xp, L); ldrift(Yp, L);
            double Rx = X.a11*Xp.a22 - X.a12*Xp.a21;
            double Ry = Y.a11*Yp.a22 - Y.a12*Yp.a21;
            double g = 0.5 * L * Rx;
            double h = 0.5 * L * Ry;
            C[0]+=g*a*a*a;   C[1]+=3.0*g*a*a*b; C[2]+=3.0*g*a*b*b; C[3]+=g*b*b*b;
            C[4]+=g*a*c2*c2; C[5]+=2.0*g*a*c2*d2; C[6]+=g*a*d2*d2;
            C[7]+=g*b*c2*c2; C[8]+=2.0*g*b*c2*d2; C[9]+=g*b*d2*d2;
            D[0]+=h*c2*c2*c2; D[1]+=3.0*h*c2*c2*d2; D[2]+=3.0*h*c2*d2*d2; D[3]+=h*d2*d2*d2;
            D[4]+=h*c2*a*a;  D[5]+=2.0*h*c2*a*b; D[6]+=h*c2*b*b;
            D[7]+=h*d2*a*a;  D[8]+=2.0*h*d2*a*b; D[9]+=h*d2*b*b;
            if (j < Q) {
                double k1 = (double)k_set[j];
                lmul(Xp, quadmatS(-k1, 1.0, 0.1));
                lmul(Yp, quadmatS( k1, 1.0, 0.1));
            }
        }
        #pragma unroll
        for (int i = 0; i < 10; ++i) { cf[32+i]=(float)C[i]; cf[42+i]=(float)D[i]; }
    }
    __syncthreads();
    if (tid < 4) {
        // Newton divided differences at the fixed nodes, fully unrolled ->
        // all-static indexing -> registers (NO scratch). Divisions are by
        // compile-time constant node differences.
        double d[NNODE];
        #pragma unroll
        for (int i = 0; i < NNODE; ++i) d[i] = Mn[i][tid];
        #pragma unroll
        for (int k = 1; k < NNODE; ++k) {
            #pragma unroll
            for (int i = NNODE - 1; i >= 1; --i) {
                if (i >= k) d[i] = (d[i] - d[i-1]) / (TN[i] - TN[i-k]);
            }
        }
        // Newton form -> monomial coeffs: P = d[7]; P = P*(t-t_i)+d[i], i=6..0
        double c[NNODE];
        c[0] = d[NNODE-1];
        #pragma unroll
        for (int k = 1; k < NNODE; ++k) c[k] = 0.0;
        #pragma unroll
        for (int i = NNODE - 2; i >= 0; --i) {
            #pragma unroll
            for (int k = NNODE - 1; k >= 1; --k) c[k] = c[k-1] - TN[i]*c[k];
            c[0] = d[i] - TN[i]*c[0];
        }
        #pragma unroll
        for (int k = 0; k < NNODE; ++k) cf[tid*8 + k] = (float)c[k];
    }
}

__device__ inline float uniformf(const float* p) {
    return __int_as_float(__builtin_amdgcn_readfirstlane(__float_as_int(*p)));
}

__global__ __launch_bounds__(256) void beam_kernel(
    const float* __restrict__ xs, const float* __restrict__ pxs,
    const float* __restrict__ ys, const float* __restrict__ pys,
    const float* __restrict__ pzs, const float* __restrict__ cf,
    int n4, int ntail, float4* __restrict__ partials)
{
    float h[32], Cx[10], Cy[10];
    #pragma unroll
    for (int k = 0; k < 32; ++k) h[k] = uniformf(cf + k);
    #pragma unroll
    for (int k = 0; k < 10; ++k) { Cx[k] = uniformf(cf + 32 + k); Cy[k] = uniformf(cf + 42 + k); }

    const float inva = (float)(1.0 / PZ_A);
    float s1x = 0.f, s2x = 0.f, s1y = 0.f, s2y = 0.f;

    auto track = [&](float x, float p, float y, float q, float pz) {
        float t = pz * inva;
        float m11 = h[7], m12 = h[15], n11 = h[23], n12 = h[31];
        #pragma unroll
        for (int k = 6; k >= 0; --k) {
            m11 = fmaf(m11, t, h[k]);
            m12 = fmaf(m12, t, h[8+k]);
            n11 = fmaf(n11, t, h[16+k]);
            n12 = fmaf(n12, t, h[24+k]);
        }
        float xx = x*x, xp = x*p, pp = p*p;
        float yy = y*y, yq = y*q, qq = q*q;
        float A1 = Cx[0]*xx; A1=fmaf(Cx[1],xp,A1); A1=fmaf(Cx[2],pp,A1);
        A1=fmaf(Cx[4],yy,A1); A1=fmaf(Cx[5],yq,A1); A1=fmaf(Cx[6],qq,A1);
        float A2 = Cx[3]*pp; A2=fmaf(Cx[7],yy,A2); A2=fmaf(Cx[8],yq,A2); A2=fmaf(Cx[9],qq,A2);
        float B1 = Cy[0]*yy; B1=fmaf(Cy[1],yq,B1); B1=fmaf(Cy[2],qq,B1);
        B1=fmaf(Cy[4],xx,B1); B1=fmaf(Cy[5],xp,B1); B1=fmaf(Cy[6],pp,B1);
        float B2 = Cy[3]*qq; B2=fmaf(Cy[7],xx,B2); B2=fmaf(Cy[8],xp,B2); B2=fmaf(Cy[9],pp,B2);
        float xf = fmaf(m11, x, m12*p); xf = fmaf(x, A1, xf); xf = fmaf(p, A2, xf);
        float yf = fmaf(n11, y, n12*q); yf = fmaf(y, B1, yf); yf = fmaf(q, B2, yf);
        s1x += xf; s2x = fmaf(xf, xf, s2x);
        s1y += yf; s2y = fmaf(yf, yf, s2y);
    };

    const int gstride = gridDim.x * blockDim.x;
    for (int i = blockIdx.x * blockDim.x + threadIdx.x; i < n4; i += gstride) {
        float4 xv  = ((const float4*)xs)[i];
        float4 pxv = ((const float4*)pxs)[i];
        float4 yv  = ((const float4*)ys)[i];
        float4 pyv = ((const float4*)pys)[i];
        float4 pzv = ((const float4*)pzs)[i];
        track(xv.x, pxv.x, yv.x, pyv.x, pzv.x);
        track(xv.y, pxv.y, yv.y, pyv.y, pzv.y);
        track(xv.z, pxv.z, yv.z, pyv.z, pzv.z);
        track(xv.w, pxv.w, yv.w, pyv.w, pzv.w);
    }
    if (blockIdx.x == 0 && threadIdx.x == 0) {
        for (int r = 0; r < ntail; ++r) {
            int idx = 4*n4 + r;
            track(xs[idx], pxs[idx], ys[idx], pys[idx], pzs[idx]);
        }
    }

    // wave (64-lane) shuffle reduce, then LDS across 4 waves
    for (int off = 32; off > 0; off >>= 1) {
        s1x += __shfl_down(s1x, off, 64);
        s2x += __shfl_down(s2x, off, 64);
        s1y += __shfl_down(s1y, off, 64);
        s2y += __shfl_down(s2y, off, 64);
    }
    __shared__ float red[4][4];
    const int lane = threadIdx.x & 63;
    const int wid  = threadIdx.x >> 6;
    if (lane == 0) {
        red[wid][0] = s1x; red[wid][1] = s2x;
        red[wid][2] = s1y; red[wid][3] = s2y;
    }
    __syncthreads();
    if (threadIdx.x == 0) {
        float a = 0.f, b = 0.f, c = 0.f, d = 0.f;
        const int nw = (blockDim.x + 63) >> 6;
        for (int w = 0; w < nw; ++w) {
            a += red[w][0]; b += red[w][1];
            c += red[w][2]; d += red[w][3];
        }
        partials[blockIdx.x] = make_float4(a, b, c, d);  // no atomics
    }
}

__global__ __launch_bounds__(256) void finalize_kernel(
    const float4* __restrict__ partials, int nparts,
    float* __restrict__ out, int N)
{
    double a = 0.0, b = 0.0, c = 0.0, d = 0.0;
    for (int i = threadIdx.x; i < nparts; i += 256) {
        float4 p = partials[i];
        a += (double)p.x; b += (double)p.y;
        c += (double)p.z; d += (double)p.w;
    }
    for (int off = 32; off > 0; off >>= 1) {
        a += __shfl_down(a, off, 64);
        b += __shfl_down(b, off, 64);
        c += __shfl_down(c, off, 64);
        d += __shfl_down(d, off, 64);
    }
    __shared__ double red[4][4];
    const int lane = threadIdx.x & 63;
    const int wid  = threadIdx.x >> 6;
    if (lane == 0) {
        red[wid][0] = a; red[wid][1] = b; red[wid][2] = c; red[wid][3] = d;
    }
    __syncthreads();
    if (threadIdx.x == 0) {
        double sa = 0, sb = 0, sc = 0, sd = 0;
        for (int w = 0; w < 4; ++w) {
            sa += red[w][0]; sb += red[w][1];
            sc += red[w][2]; sd += red[w][3];
        }
        const double n  = (double)N;
        const double vx = (sb - sa*sa/n) / (n - 1.0);
        const double vy = (sd - sc*sc/n) / (n - 1.0);
        const double dx = sqrt(vx) - SIGMA_T;
        const double dy = sqrt(vy) - SIGMA_T;
        out[0] = (float)sqrt(dx*dx + dy*dy);
    }
}

extern "C" void kernel_launch(void* const* d_in, const int* in_sizes, int n_in,
                              void* d_out, int out_size, void* d_ws, size_t ws_size,
                              hipStream_t stream) {
    const float* xs  = (const float*)d_in[0];
    const float* pxs = (const float*)d_in[1];
    const float* ys  = (const float*)d_in[2];
    const float* pys = (const float*)d_in[3];
    // d_in[4] = z : dead
    const float* pzs = (const float*)d_in[5];
    const float* ks  = (const float*)d_in[6];
    // d_in[7] = n_slices : dead (exact slice composition)

    const int N = in_sizes[0];
    const int Q = in_sizes[6];

    float*  cf       = (float*)((char*)d_ws + 64);
    float4* partials = (float4*)((char*)d_ws + 4096);

    prep_kernel<<<1, 128, 0, stream>>>(ks, Q, cf);

    const int n4 = N >> 2;
    const int ntail = N & 3;
    int blocks = (n4 + 255) / 256;
    if (blocks < 1) blocks = 1;
    if (blocks > MAXBLK) blocks = MAXBLK;
    beam_kernel<<<blocks, 256, 0, stream>>>(xs, pxs, ys, pys, pzs, cf, n4, ntail, partials);
    finalize_kernel<<<1, 256, 0, stream>>>(partials, blocks, (float*)d_out, N);
}